// Round 1
// baseline (112.749 us; speedup 1.0000x reference)
//
#include <hip/hip_runtime.h>

typedef unsigned short u16;
typedef __attribute__((ext_vector_type(8))) short bf16x8;
typedef __attribute__((ext_vector_type(4))) float f32x4;

#define NUM_OPS 8
#define M_DIM 4096   // B*T = 8*512
#define K_DIM 1024
#define N_DIM 1024

// ---- helpers ----------------------------------------------------------

__device__ __forceinline__ u16 f2b(float f) {
  union { float f; unsigned u; } v; v.f = f;
  unsigned r = v.u + 0x7fffu + ((v.u >> 16) & 1u);  // RNE
  return (u16)(r >> 16);
}

__device__ __forceinline__ int compute_idx(const float* __restrict__ logits,
                                           const float* __restrict__ u) {
  // argmax(log_softmax(logits) + gumbel) == argmax(logits - log(-log(u)))
  int best = 0; float bv = -3.4e38f;
#pragma unroll
  for (int i = 0; i < NUM_OPS; ++i) {
    float g = -logf(-logf(u[i]));
    float v = logits[i] + g;
    if (v > bv) { bv = v; best = i; }
  }
  return best;
}

// async global->LDS, 16B per lane; LDS dest = wave-uniform base + lane*16
__device__ __forceinline__ void gld_lds16(const void* g, void* l) {
  __builtin_amdgcn_global_load_lds(
      (__attribute__((address_space(1))) void*)(g),
      (__attribute__((address_space(3))) void*)(unsigned)(unsigned long long)(l),
      16, 0, 0);
}

// ---- prep: idx select, x -> bf16, W[idx] -> W^T bf16 ------------------
// grid: 2048 blocks x-convert + 256 blocks W-transpose, 256 thr
__global__ void prep_kernel(const float* __restrict__ x, const float* __restrict__ W,
                            const float* __restrict__ logits, const float* __restrict__ u,
                            u16* __restrict__ xb, u16* __restrict__ wt) {
  const int tid = threadIdx.x;
  const int bid = blockIdx.x;
  if (bid < 2048) {
    // 8 floats / thread, vectorized
    size_t i0 = ((size_t)bid * 256 + tid) * 8;
    const float4* xp = (const float4*)(x + i0);
    float4 f0 = xp[0], f1 = xp[1];
    unsigned p0 = (unsigned)f2b(f0.x) | ((unsigned)f2b(f0.y) << 16);
    unsigned p1 = (unsigned)f2b(f0.z) | ((unsigned)f2b(f0.w) << 16);
    unsigned p2 = (unsigned)f2b(f1.x) | ((unsigned)f2b(f1.y) << 16);
    unsigned p3 = (unsigned)f2b(f1.z) | ((unsigned)f2b(f1.w) << 16);
    uint4 pk; pk.x = p0; pk.y = p1; pk.z = p2; pk.w = p3;
    *(uint4*)(xb + i0) = pk;
  } else {
    // transpose+convert one 64x64 tile of W[idx]
    __shared__ u16 t[64][66];  // +2 pad: column reads conflict-free
    const int wb = bid - 2048;
    const int kt = wb >> 4, nt = wb & 15;
    const int idx = compute_idx(logits, u);
    const float* Wi = W + (size_t)idx * K_DIM * N_DIM;
#pragma unroll
    for (int it = 0; it < 16; ++it) {
      int i = it * 256 + tid;
      int r = i >> 6, c = i & 63;
      t[r][c] = f2b(Wi[(size_t)(kt * 64 + r) * N_DIM + nt * 64 + c]);
    }
    __syncthreads();
#pragma unroll
    for (int it = 0; it < 16; ++it) {
      int i = it * 256 + tid;
      int n = i >> 6, k = i & 63;
      wt[(size_t)(nt * 64 + n) * K_DIM + kt * 64 + k] = t[k][n];
    }
  }
}

// ---- GEMM: C = Xb * Wt^T (+ b[idx]) -----------------------------------
// BM=128, BN=64, BK=32; 256 thr = 4 waves in 2x2; wave tile 64x32
__global__ __launch_bounds__(256) void gemm_kernel(
    const u16* __restrict__ xb, const u16* __restrict__ wt,
    const float* __restrict__ bvec, const float* __restrict__ logits,
    const float* __restrict__ u, float* __restrict__ out) {
  __shared__ u16 sA[128 * 32];  // [m][k] rows of 32 bf16 (64B)
  __shared__ u16 sB[64 * 32];   // [n][k] rows of 32 bf16

  const int tid = threadIdx.x;
  const int w = tid >> 6, L = tid & 63;
  const int m0 = blockIdx.y * 128;
  const int n0 = blockIdx.x * 64;

  // staging: wave w loads A rows [32w,32w+32) (2 issues) and B rows [16w,16w+16)
  const int q0 = 2 * w, q1 = 2 * w + 1;
  const u16* gA0 = xb + (size_t)(m0 + 16 * q0 + (L >> 2)) * K_DIM + (L & 3) * 8;
  const u16* gA1 = xb + (size_t)(m0 + 16 * q1 + (L >> 2)) * K_DIM + (L & 3) * 8;
  const u16* gB0 = wt + (size_t)(n0 + 16 * w + (L >> 2)) * K_DIM + (L & 3) * 8;
  u16* lA0 = sA + q0 * 512 + L * 8;  // ushort units: q*1024B + L*16B
  u16* lA1 = sA + q1 * 512 + L * 8;
  u16* lB0 = sB + w * 512 + L * 8;

  const int wm = w & 1, wn = w >> 1;
  int aoff[4], boff[2];
#pragma unroll
  for (int mt = 0; mt < 4; ++mt)
    aoff[mt] = (64 * wm + 16 * mt + (L & 15)) * 32 + (L >> 4) * 8;
#pragma unroll
  for (int nt = 0; nt < 2; ++nt)
    boff[nt] = (32 * wn + 16 * nt + (L & 15)) * 32 + (L >> 4) * 8;

  f32x4 acc[4][2] = {};

  for (int kk = 0; kk < K_DIM / 32; ++kk) {
    __syncthreads();          // previous iter's ds_reads done before overwrite
    gld_lds16(gA0, lA0);
    gld_lds16(gA1, lA1);
    gld_lds16(gB0, lB0);
    gA0 += 32; gA1 += 32; gB0 += 32;
    __syncthreads();          // emits s_waitcnt vmcnt(0) -> staging visible

    bf16x8 af[4], bf[2];
#pragma unroll
    for (int mt = 0; mt < 4; ++mt) af[mt] = *(const bf16x8*)(sA + aoff[mt]);
#pragma unroll
    for (int nt = 0; nt < 2; ++nt) bf[nt] = *(const bf16x8*)(sB + boff[nt]);
#pragma unroll
    for (int mt = 0; mt < 4; ++mt)
#pragma unroll
      for (int nt = 0; nt < 2; ++nt)
        acc[mt][nt] = __builtin_amdgcn_mfma_f32_16x16x32_bf16(
            af[mt], bf[nt], acc[mt][nt], 0, 0, 0);
  }

  // epilogue: C/D layout col=lane&15, row=(lane>>4)*4+reg
  const int idx = compute_idx(logits, u);
  const float* bi = bvec + (size_t)idx * N_DIM;
#pragma unroll
  for (int mt = 0; mt < 4; ++mt) {
    int row = m0 + 64 * wm + 16 * mt + (L >> 4) * 4;
#pragma unroll
    for (int nt = 0; nt < 2; ++nt) {
      int col = n0 + 32 * wn + 16 * nt + (L & 15);
      float bv = bi[col];
#pragma unroll
      for (int r = 0; r < 4; ++r)
        out[(size_t)(row + r) * N_DIM + col] = acc[mt][nt][r] + bv;
    }
  }
}

// ---- launch -----------------------------------------------------------

extern "C" void kernel_launch(void* const* d_in, const int* in_sizes, int n_in,
                              void* d_out, int out_size, void* d_ws, size_t ws_size,
                              hipStream_t stream) {
  const float* x      = (const float*)d_in[0];
  const float* W      = (const float*)d_in[1];
  const float* bvec   = (const float*)d_in[2];
  const float* logits = (const float*)d_in[3];
  const float* u      = (const float*)d_in[4];
  float* out = (float*)d_out;

  u16* xb = (u16*)d_ws;                       // 4096*1024 bf16 = 8 MB
  u16* wt = (u16*)d_ws + (size_t)M_DIM * K_DIM;  // 1024*1024 bf16 = 2 MB

  prep_kernel<<<2048 + 256, 256, 0, stream>>>(x, W, logits, u, xb, wt);
  dim3 grid(N_DIM / 64, M_DIM / 128);
  gemm_kernel<<<grid, 256, 0, stream>>>(xb, wt, bvec, logits, u, out);
}